// Round 7
// baseline (8147.245 us; speedup 1.0000x reference)
//
#include <hip/hip_runtime.h>
#include <stdint.h>

typedef uint32_t u32; typedef uint16_t u16;
typedef __attribute__((ext_vector_type(8))) __bf16 bf16x8;
typedef __attribute__((ext_vector_type(4))) float f32x4;
typedef __attribute__((ext_vector_type(2))) u32 u32x2;
typedef __attribute__((ext_vector_type(4))) u32 u32x4;

#define Vv 50000
#define Ee 256
#define Hh 256
#define Gg 768
#define Bb 64
#define Tt 2048

__device__ __forceinline__ u16 f2bf(float f) {
  u32 x = __builtin_bit_cast(u32, f);
  return (u16)((x + 0x7FFFu + ((x >> 16) & 1u)) >> 16);
}
__device__ __forceinline__ u32 pack2(float a, float b) {
  return (u32)f2bf(a) | ((u32)f2bf(b) << 16);
}
__device__ __forceinline__ float sigm(float x) {
  float e = __builtin_amdgcn_exp2f(-1.44269504089f * x);
  return __builtin_amdgcn_rcpf(1.0f + e);
}
__device__ __forceinline__ float tanh_fast(float x) {
  float e = __builtin_amdgcn_exp2f(2.88539008178f * x);
  return 1.0f - 2.0f * __builtin_amdgcn_rcpf(e + 1.0f);
}
__device__ __forceinline__ float bflo(u32 v) { return __builtin_bit_cast(float, v << 16); }
__device__ __forceinline__ float bfhi(u32 v) { return __builtin_bit_cast(float, v & 0xffff0000u); }

// LDS-only barrier: gi gather loads (lane-private) stay in flight across it.
__device__ __forceinline__ void block_sync_lds() {
  asm volatile("s_waitcnt lgkmcnt(0)" ::: "memory");
  __builtin_amdgcn_s_barrier();
  asm volatile("" ::: "memory");
}

// ---------------- K0: bias row (row Vv) of both P tables ----------------
__global__ void k0_bias(const float* __restrict__ bih_f, const float* __restrict__ bhh_f,
                        const float* __restrict__ bih_b, const float* __restrict__ bhh_b,
                        u16* __restrict__ Pf, u16* __restrict__ Pb) {
  int c = threadIdx.x + blockIdx.x * 256;
  if (c < Gg) {
    float bf_ = bih_f[c] + (c < 512 ? bhh_f[c] : 0.f);
    float bb_ = bih_b[c] + (c < 512 ? bhh_b[c] : 0.f);
    Pf[(size_t)Vv * Gg + c] = f2bf(bf_);
    Pb[(size_t)Vv * Gg + c] = f2bf(bb_);
  }
}

// ---------------- K1: P'[v,g] = emb[v]@W_ih^T + bias (bf16) ----------------
__global__ __launch_bounds__(256) void k1_proj(
    const float* __restrict__ emb, const float* __restrict__ Wih_f,
    const float* __restrict__ Wih_b,
    const float* __restrict__ bih_f, const float* __restrict__ bhh_f,
    const float* __restrict__ bih_b, const float* __restrict__ bhh_b,
    u16* __restrict__ Pf, u16* __restrict__ Pb)
{
  const int t = threadIdx.x, w = t >> 6, l = t & 63;
  const int cl = l & 15, rq = l >> 4;
  const int m0 = blockIdx.x * 128;
  const int dir = blockIdx.y;
  const int nbase = blockIdx.z * 3;
  const float* Wih = dir ? Wih_b : Wih_f;
  const float* bih = dir ? bih_b : bih_f;
  const float* bhh = dir ? bhh_b : bhh_f;
  u16* Pd = dir ? Pb : Pf;

  __shared__ __align__(16) u16 As[4096 * 8];
  __shared__ __align__(16) u16 Bs[2048 * 8];

  for (int i = t; i < 4096; i += 256) {
    const int kt = i >> 9, rem = i & 511, row = rem >> 2, rqv = rem & 3;
    const int gm = m0 + row;
    float4 a0 = {0.f,0.f,0.f,0.f}, a1 = {0.f,0.f,0.f,0.f};
    if (gm < Vv) {
      const float* src = emb + (size_t)gm * Ee + kt * 32 + rqv * 8;
      a0 = *(const float4*)src;
      a1 = *(const float4*)(src + 4);
    }
    u32x4 uv = { pack2(a0.x, a0.y), pack2(a0.z, a0.w),
                 pack2(a1.x, a1.y), pack2(a1.z, a1.w) };
    *(u32x4*)(As + (size_t)i * 8) = uv;
  }
  __syncthreads();

  for (int nbo = 0; nbo < 3; ++nbo) {
    const int nb = nbase + nbo;
    for (int i = t; i < 2048; i += 256) {
      const int kt = i >> 8, rem = i & 255, r2 = rem >> 2, rqv = rem & 3;
      const float* src = Wih + (size_t)(nb * 64 + r2) * Ee + kt * 32 + rqv * 8;
      const float4 b0 = *(const float4*)src;
      const float4 b1 = *(const float4*)(src + 4);
      u32x4 uv = { pack2(b0.x, b0.y), pack2(b0.z, b0.w),
                   pack2(b1.x, b1.y), pack2(b1.z, b1.w) };
      *(u32x4*)(Bs + (size_t)i * 8) = uv;
    }
    __syncthreads();

    f32x4 zero4 = {0.f, 0.f, 0.f, 0.f};
    f32x4 acc[2][4];
#pragma unroll
    for (int mt = 0; mt < 2; ++mt)
#pragma unroll
      for (int nt = 0; nt < 4; ++nt) acc[mt][nt] = zero4;

#pragma unroll
    for (int kt = 0; kt < 8; ++kt) {
      bf16x8 af[2], bfr[4];
#pragma unroll
      for (int mt = 0; mt < 2; ++mt)
        af[mt] = *(const bf16x8*)(As + ((size_t)kt * 512 + (w * 32 + mt * 16 + cl) * 4 + rq) * 8);
#pragma unroll
      for (int nt = 0; nt < 4; ++nt)
        bfr[nt] = *(const bf16x8*)(Bs + ((size_t)kt * 256 + (nt * 16 + cl) * 4 + rq) * 8);
#pragma unroll
      for (int mt = 0; mt < 2; ++mt)
#pragma unroll
        for (int nt = 0; nt < 4; ++nt)
          acc[mt][nt] = __builtin_amdgcn_mfma_f32_16x16x32_bf16(af[mt], bfr[nt], acc[mt][nt], 0, 0, 0);
    }

#pragma unroll
    for (int mt = 0; mt < 2; ++mt)
#pragma unroll
      for (int nt = 0; nt < 4; ++nt) {
        const int col = nb * 64 + nt * 16 + cl;
        float bias = bih[col];
        if (col < 512) bias += bhh[col];
#pragma unroll
        for (int q = 0; q < 4; ++q) {
          const int row = m0 + w * 32 + mt * 16 + rq * 4 + q;
          if (row < Vv) Pd[(size_t)row * Gg + col] = f2bf(acc[mt][nt][q] + bias);
        }
      }
    __syncthreads();
  }
}

// ---------------- K2: bidirectional GRU recurrence (4 waves, 512-reg budget) ----
// 8 blocks (dir = blk>>2, 16 batch rows), 256 threads = 4 waves, 1 wave/SIMD.
// Each wave owns 4 h-units x 3 gates = 192 gate cols; wfrag[3][4][8] = 384
// VGPRs/lane -- FITS in the 512-reg budget at 1 wave/EU (the r1-r6 versions
// spilled wfrag to scratch: VGPR=128 < 192 needed; WRITE_SIZE ~4MB = spill
// store; per-step L2 re-read ~7000cyc/step = observed). b_hh_n and h-prev
// come from LDS (broadcast / own-slot reads) to keep pressure down.
__global__ __launch_bounds__(256) __attribute__((amdgpu_waves_per_eu(1, 1)))
void k2_rec(
    const int* __restrict__ seqs, const int* __restrict__ lens,
    const float* __restrict__ Whh_f, const float* __restrict__ Whh_b,
    const float* __restrict__ bhh_f, const float* __restrict__ bhh_b,
    const u16* __restrict__ Pf, const u16* __restrict__ Pb,
    float* __restrict__ rep)
{
  const int tid = threadIdx.x, w = tid >> 6, l = tid & 63;
  const int cl = l & 15, rq = l >> 4;
  const int dir = (int)blockIdx.x >> 2;
  const int b0 = ((int)blockIdx.x & 3) * 16;

  const float* Whh = dir ? Whh_b : Whh_f;
  const float* bhh = dir ? bhh_b : bhh_f;
  const u16* P = dir ? Pb : Pf;

  __shared__ __align__(16) u16 h_lds[8192];    // 16 KB: 2 bufs x [kb][row][j^]
  __shared__ __align__(16) float bhn_lds[256]; // b_hh_n, broadcast reads

  // ---- W_hh A-fragments: 3 gates x 4 units x 8 kb = 384 regs/lane ----
  bf16x8 wfrag[3][4][8];
#pragma unroll
  for (int g = 0; g < 3; ++g)
#pragma unroll
    for (int bi = 0; bi < 4; ++bi) {
      const int c = g * 256 + (4 * w + bi) * 16 + cl;
      const float* wr = Whh + (size_t)c * Hh;
#pragma unroll
      for (int kb = 0; kb < 8; ++kb) {
        const int k0 = kb * 32 + rq * 8;
        const float4 f0 = *(const float4*)(wr + k0);
        const float4 f1 = *(const float4*)(wr + k0 + 4);
        u32x4 uv = { pack2(f0.x, f0.y), pack2(f0.z, f0.w),
                     pack2(f1.x, f1.y), pack2(f1.z, f1.w) };
        wfrag[g][bi][kb] = __builtin_bit_cast(bf16x8, uv);
      }
    }

  bhn_lds[tid] = bhh[512 + tid];               // 256 threads, one each

  const int myrow = b0 + cl;
  const int mylen = lens[myrow];
  const int* myseq = seqs + (size_t)myrow * Tt;
  const int vthr = Tt - mylen;

  for (int i = tid; i < 4096; i += 256) ((u32*)h_lds)[i] = 0;

  // lane LDS byte offsets (XOR-swizzled fragment layout; verified r3-r6)
  const int xk = (cl >> 1);
  const int rdoff = cl * 64 + (((rq + xk) & 3) << 4);            // + kb*1024
  const int wro0 = (2 * w + 0) * 1024 + cl * 64 + ((((rq >> 1) + 0 + xk) & 3) << 4) + (rq & 1) * 8;
  const int wro1 = (2 * w + 0) * 1024 + cl * 64 + ((((rq >> 1) + 2 + xk) & 3) << 4) + (rq & 1) * 8;
  const int wro2 = (2 * w + 1) * 1024 + cl * 64 + ((((rq >> 1) + 0 + xk) & 3) << 4) + (rq & 1) * 8;
  const int wro3 = (2 * w + 1) * 1024 + cl * 64 + ((((rq >> 1) + 2 + xk) & 3) << 4) + (rq & 1) * 8;

  const int colb0 = w * 64 + rq * 4;   // u16 offset of (bi=0) gi chunk in a P row

  // ---- prologue: gi(0) into regs; token for step 1 ----
  u32x2 gi[3][4];
  {
    const int tk = myseq[dir ? (Tt - 1) : 0];
    const int valid = dir ? (0 < mylen) : (0 >= vthr);
    const u32 off = (valid ? (u32)tk : (u32)Vv) * (u32)(Gg * 2);
    const u16* pr = (const u16*)((const char*)P + off) + colb0;
#pragma unroll
    for (int g = 0; g < 3; ++g)
#pragma unroll
      for (int bi = 0; bi < 4; ++bi)
        gi[g][bi] = *(const u32x2*)(pr + g * 256 + bi * 16);
  }
  int tok1 = myseq[dir ? (Tt - 2) : 1];
  block_sync_lds();

#define MFMA12(HF, KB)                                                              \
  ar0 = __builtin_amdgcn_mfma_f32_16x16x32_bf16(wfrag[0][0][KB], HF, ar0, 0, 0, 0); \
  az0 = __builtin_amdgcn_mfma_f32_16x16x32_bf16(wfrag[1][0][KB], HF, az0, 0, 0, 0); \
  an0 = __builtin_amdgcn_mfma_f32_16x16x32_bf16(wfrag[2][0][KB], HF, an0, 0, 0, 0); \
  ar1 = __builtin_amdgcn_mfma_f32_16x16x32_bf16(wfrag[0][1][KB], HF, ar1, 0, 0, 0); \
  az1 = __builtin_amdgcn_mfma_f32_16x16x32_bf16(wfrag[1][1][KB], HF, az1, 0, 0, 0); \
  an1 = __builtin_amdgcn_mfma_f32_16x16x32_bf16(wfrag[2][1][KB], HF, an1, 0, 0, 0); \
  ar2 = __builtin_amdgcn_mfma_f32_16x16x32_bf16(wfrag[0][2][KB], HF, ar2, 0, 0, 0); \
  az2 = __builtin_amdgcn_mfma_f32_16x16x32_bf16(wfrag[1][2][KB], HF, az2, 0, 0, 0); \
  an2 = __builtin_amdgcn_mfma_f32_16x16x32_bf16(wfrag[2][2][KB], HF, an2, 0, 0, 0); \
  ar3 = __builtin_amdgcn_mfma_f32_16x16x32_bf16(wfrag[0][3][KB], HF, ar3, 0, 0, 0); \
  az3 = __builtin_amdgcn_mfma_f32_16x16x32_bf16(wfrag[1][3][KB], HF, az3, 0, 0, 0); \
  an3 = __builtin_amdgcn_mfma_f32_16x16x32_bf16(wfrag[2][3][KB], HF, an3, 0, 0, 0);

  int bb = 0;
  for (int s = 0; s < Tt; ++s) {
    const char* hb = (const char*)h_lds + bb;
    char* hn = (char*)h_lds + (bb ^ 8192);

    // ---- MFMA phase: 96 MFMAs, 2-deep pipelined h-fragment stream ----
    f32x4 zero4 = {0.f, 0.f, 0.f, 0.f};
    f32x4 ar0 = zero4, az0 = zero4, an0 = zero4, ar1 = zero4, az1 = zero4, an1 = zero4;
    f32x4 ar2 = zero4, az2 = zero4, an2 = zero4, ar3 = zero4, az3 = zero4, an3 = zero4;

    bf16x8 hA = *(const bf16x8*)(hb + rdoff);
    bf16x8 hB;
#pragma unroll
    for (int kb = 0; kb < 8; kb += 2) {
      hB = *(const bf16x8*)(hb + (kb + 1) * 1024 + rdoff);
      MFMA12(hA, kb)
      if (kb + 2 < 8) hA = *(const bf16x8*)(hb + (kb + 2) * 1024 + rdoff);
      MFMA12(hB, kb + 1)
    }

    // token for s+2
    int tok2 = tok1;
    if (s + 2 < Tt) tok2 = myseq[dir ? (Tt - 3 - s) : (s + 2)];

    // gi row pointer for s+1
    const int validn = dir ? (s + 1 < mylen) : (s + 1 >= vthr);
    const u32 offn = (validn ? (u32)tok1 : (u32)Vv) * (u32)(Gg * 2);
    const u16* prn = (const u16*)((const char*)P + offn) + colb0;

    // ---- GATES per unit (b_hh_n + h-prev from LDS; gi reload at tail) ----
#define GATES(BI, AR, AZ, AN, WRO)                                                \
    {                                                                             \
      const f32x4 bhnv = *(const f32x4*)((const char*)bhn_lds + (4 * w + BI) * 64 + rq * 16); \
      const u32x2 hp = *(const u32x2*)(hb + WRO);                                 \
      float hq[4];                                                                \
      _Pragma("unroll")                                                           \
      for (int q = 0; q < 4; ++q) {                                               \
        const u32 wr_ = (q & 2) ? gi[0][BI][1] : gi[0][BI][0];                    \
        const u32 wz_ = (q & 2) ? gi[1][BI][1] : gi[1][BI][0];                    \
        const u32 wn_ = (q & 2) ? gi[2][BI][1] : gi[2][BI][0];                    \
        const float ir = (q & 1) ? bfhi(wr_) : bflo(wr_);                         \
        const float iz = (q & 1) ? bfhi(wz_) : bflo(wz_);                         \
        const float in_ = (q & 1) ? bfhi(wn_) : bflo(wn_);                        \
        const float r = sigm(ir + AR[q]);                                         \
        const float z = sigm(iz + AZ[q]);                                         \
        const float t_ = fmaf(r, bhnv[q], in_);                                   \
        const float n = tanh_fast(fmaf(r, AN[q], t_));                            \
        const float hpq = (q & 1) ? bfhi(hp[q >> 1]) : bflo(hp[q >> 1]);          \
        hq[q] = fmaf(z, hpq - n, n);                                              \
      }                                                                           \
      u32 p0, p1;                                                                 \
      asm("v_cvt_pk_bf16_f32 %0, %1, %2" : "=v"(p0) : "v"(hq[0]), "v"(hq[1]));    \
      asm("v_cvt_pk_bf16_f32 %0, %1, %2" : "=v"(p1) : "v"(hq[2]), "v"(hq[3]));    \
      u32x2 hw = {p0, p1};                                                        \
      *(u32x2*)(hn + WRO) = hw;                                                   \
      _Pragma("unroll")                                                           \
      for (int g = 0; g < 3; ++g) gi[g][BI] = *(const u32x2*)(prn + g * 256 + BI * 16); \
    }

    GATES(0, ar0, az0, an0, wro0)
    GATES(1, ar1, az1, an1, wro1)
    GATES(2, ar2, az2, an2, wro2)
    GATES(3, ar3, az3, an3, wro3)
#undef GATES

    tok1 = tok2;
    bb ^= 8192;
    block_sync_lds();
  }
#undef MFMA12

  // ---- final h (buffer 0, this lane's own slots) -> rep ----
  {
    const char* hf_ = (const char*)h_lds;    // Tt even -> final state in buf 0
    const u32x2 f0 = *(const u32x2*)(hf_ + wro0);
    const u32x2 f1 = *(const u32x2*)(hf_ + wro1);
    const u32x2 f2 = *(const u32x2*)(hf_ + wro2);
    const u32x2 f3 = *(const u32x2*)(hf_ + wro3);
    float* rp = rep + (size_t)(b0 + cl) * (2 * Hh) + dir * Hh + w * 64 + rq * 4;
    rp[0]  = bflo(f0[0]); rp[1]  = bfhi(f0[0]); rp[2]  = bflo(f0[1]); rp[3]  = bfhi(f0[1]);
    rp[16] = bflo(f1[0]); rp[17] = bfhi(f1[0]); rp[18] = bflo(f1[1]); rp[19] = bfhi(f1[1]);
    rp[32] = bflo(f2[0]); rp[33] = bfhi(f2[0]); rp[34] = bflo(f2[1]); rp[35] = bfhi(f2[1]);
    rp[48] = bflo(f3[0]); rp[49] = bfhi(f3[0]); rp[50] = bflo(f3[1]); rp[51] = bfhi(f3[1]);
  }
}

// ---------------- K3a: h1 = relu(rep @ W1^T + b1) ----------------
__global__ __launch_bounds__(256) void k3a(
    const float* __restrict__ rep, const float* __restrict__ W1,
    const float* __restrict__ b1, float* __restrict__ h1)
{
  __shared__ float rl[512];
  const int b = blockIdx.x, t = threadIdx.x;
  rl[t] = rep[(size_t)b * 512 + t];
  rl[t + 256] = rep[(size_t)b * 512 + 256 + t];
  __syncthreads();
#pragma unroll
  for (int oo = 0; oo < 2; ++oo) {
    const int o = t + oo * 256;
    const float4* wr = (const float4*)(W1 + (size_t)o * 512);
    const float4* rr = (const float4*)rl;
    float acc = 0.f;
#pragma unroll 8
    for (int k = 0; k < 128; ++k) {
      const float4 wv = wr[k], rv = rr[k];
      acc += wv.x * rv.x + wv.y * rv.y + wv.z * rv.z + wv.w * rv.w;
    }
    h1[(size_t)b * 512 + o] = fmaxf(acc + b1[o], 0.f);
  }
}

// ---------------- K3b: out = softmax(h1 @ W2^T + b2) ----------------
__global__ __launch_bounds__(320) void k3b(
    const float* __restrict__ h1, const float* __restrict__ W2,
    const float* __restrict__ b2, float* __restrict__ out)
{
  __shared__ float lg[64 * 5];
  const int t = threadIdx.x;      // 320 = 5 classes x 64 batch
  const int c = t >> 6, b = t & 63;
  const float4* hr = (const float4*)(h1 + (size_t)b * 512);
  const float4* wr = (const float4*)(W2 + (size_t)c * 512);
  float acc = 0.f;
#pragma unroll 8
  for (int k = 0; k < 128; ++k) {
    const float4 hv = hr[k], wv = wr[k];
    acc += hv.x * wv.x + hv.y * wv.y + hv.z * wv.z + hv.w * wv.w;
  }
  lg[b * 5 + c] = acc + b2[c];
  __syncthreads();
  if (t < 64) {
    float v[5];
#pragma unroll
    for (int i = 0; i < 5; ++i) v[i] = lg[t * 5 + i];
    float m = v[0];
#pragma unroll
    for (int i = 1; i < 5; ++i) m = fmaxf(m, v[i]);
    float ssum = 0.f;
#pragma unroll
    for (int i = 0; i < 5; ++i) {
      v[i] = __builtin_amdgcn_exp2f(1.44269504089f * (v[i] - m));
      ssum += v[i];
    }
    const float inv = 1.0f / ssum;
#pragma unroll
    for (int i = 0; i < 5; ++i) out[t * 5 + i] = v[i] * inv;
  }
}

extern "C" void kernel_launch(void* const* d_in, const int* in_sizes, int n_in,
                              void* d_out, int out_size, void* d_ws, size_t ws_size,
                              hipStream_t stream) {
  const int* seqs = (const int*)d_in[0];
  const int* lens = (const int*)d_in[1];
  const float* emb = (const float*)d_in[2];
  const float* Wih_f = (const float*)d_in[3];
  const float* Whh_f = (const float*)d_in[4];
  const float* bih_f = (const float*)d_in[5];
  const float* bhh_f = (const float*)d_in[6];
  const float* Wih_b = (const float*)d_in[7];
  const float* Whh_b = (const float*)d_in[8];
  const float* bih_b = (const float*)d_in[9];
  const float* bhh_b = (const float*)d_in[10];
  const float* W1 = (const float*)d_in[11];
  const float* b1 = (const float*)d_in[12];
  const float* W2 = (const float*)d_in[13];
  const float* b2 = (const float*)d_in[14];
  float* out = (float*)d_out;

  char* ws = (char*)d_ws;
  const size_t PSZ = (size_t)(Vv + 1) * Gg * 2;   // 76,801,536 B per direction
  u16* Pf = (u16*)ws;
  u16* Pb = (u16*)(ws + PSZ);
  float* rep = (float*)(ws + 2 * PSZ);
  float* h1 = (float*)(ws + 2 * PSZ + 131072);

  hipLaunchKernelGGL(k0_bias, dim3(3), dim3(256), 0, stream,
                     bih_f, bhh_f, bih_b, bhh_b, Pf, Pb);
  hipLaunchKernelGGL(k1_proj, dim3(391, 2, 4), dim3(256), 0, stream,
                     emb, Wih_f, Wih_b, bih_f, bhh_f, bih_b, bhh_b, Pf, Pb);
  hipLaunchKernelGGL(k2_rec, dim3(8), dim3(256), 0, stream,
                     seqs, lens, Whh_f, Whh_b, bhh_f, bhh_b, Pf, Pb, rep);
  hipLaunchKernelGGL(k3a, dim3(64), dim3(256), 0, stream, rep, W1, b1, h1);
  hipLaunchKernelGGL(k3b, dim3(1), dim3(320), 0, stream, h1, W2, b2, out);
}

// Round 8
// 5708.423 us; speedup vs baseline: 1.4272x; 1.4272x over previous
//
#include <hip/hip_runtime.h>
#include <stdint.h>

typedef uint32_t u32; typedef uint16_t u16;
typedef __attribute__((ext_vector_type(8))) __bf16 bf16x8;
typedef __attribute__((ext_vector_type(4))) float f32x4;
typedef __attribute__((ext_vector_type(2))) u32 u32x2;
typedef __attribute__((ext_vector_type(4))) u32 u32x4;

#define Vv 50000
#define Ee 256
#define Hh 256
#define Gg 768
#define Bb 64
#define Tt 2048

__device__ __forceinline__ u16 f2bf(float f) {
  u32 x = __builtin_bit_cast(u32, f);
  return (u16)((x + 0x7FFFu + ((x >> 16) & 1u)) >> 16);
}
__device__ __forceinline__ u32 pack2(float a, float b) {
  return (u32)f2bf(a) | ((u32)f2bf(b) << 16);
}
__device__ __forceinline__ float sigm(float x) {
  float e = __builtin_amdgcn_exp2f(-1.44269504089f * x);
  return __builtin_amdgcn_rcpf(1.0f + e);
}
__device__ __forceinline__ float tanh_fast(float x) {
  float e = __builtin_amdgcn_exp2f(2.88539008178f * x);
  return 1.0f - 2.0f * __builtin_amdgcn_rcpf(e + 1.0f);
}
__device__ __forceinline__ float bflo(u32 v) { return __builtin_bit_cast(float, v << 16); }
__device__ __forceinline__ float bfhi(u32 v) { return __builtin_bit_cast(float, v & 0xffff0000u); }

// LDS-only barrier: gi gather loads (lane-private) stay in flight across it.
__device__ __forceinline__ void block_sync_lds() {
  asm volatile("s_waitcnt lgkmcnt(0)" ::: "memory");
  __builtin_amdgcn_s_barrier();
  asm volatile("" ::: "memory");
}

// ---------------- K0: bias row (row Vv) of both P tables ----------------
__global__ void k0_bias(const float* __restrict__ bih_f, const float* __restrict__ bhh_f,
                        const float* __restrict__ bih_b, const float* __restrict__ bhh_b,
                        u16* __restrict__ Pf, u16* __restrict__ Pb) {
  int c = threadIdx.x + blockIdx.x * 256;
  if (c < Gg) {
    float bf_ = bih_f[c] + (c < 512 ? bhh_f[c] : 0.f);
    float bb_ = bih_b[c] + (c < 512 ? bhh_b[c] : 0.f);
    Pf[(size_t)Vv * Gg + c] = f2bf(bf_);
    Pb[(size_t)Vv * Gg + c] = f2bf(bb_);
  }
}

// ---------------- K1: P'[v,g] = emb[v]@W_ih^T + bias (bf16) ----------------
__global__ __launch_bounds__(256) void k1_proj(
    const float* __restrict__ emb, const float* __restrict__ Wih_f,
    const float* __restrict__ Wih_b,
    const float* __restrict__ bih_f, const float* __restrict__ bhh_f,
    const float* __restrict__ bih_b, const float* __restrict__ bhh_b,
    u16* __restrict__ Pf, u16* __restrict__ Pb)
{
  const int t = threadIdx.x, w = t >> 6, l = t & 63;
  const int cl = l & 15, rq = l >> 4;
  const int m0 = blockIdx.x * 128;
  const int dir = blockIdx.y;
  const int nbase = blockIdx.z * 3;
  const float* Wih = dir ? Wih_b : Wih_f;
  const float* bih = dir ? bih_b : bih_f;
  const float* bhh = dir ? bhh_b : bhh_f;
  u16* Pd = dir ? Pb : Pf;

  __shared__ __align__(16) u16 As[4096 * 8];
  __shared__ __align__(16) u16 Bs[2048 * 8];

  for (int i = t; i < 4096; i += 256) {
    const int kt = i >> 9, rem = i & 511, row = rem >> 2, rqv = rem & 3;
    const int gm = m0 + row;
    float4 a0 = {0.f,0.f,0.f,0.f}, a1 = {0.f,0.f,0.f,0.f};
    if (gm < Vv) {
      const float* src = emb + (size_t)gm * Ee + kt * 32 + rqv * 8;
      a0 = *(const float4*)src;
      a1 = *(const float4*)(src + 4);
    }
    u32x4 uv = { pack2(a0.x, a0.y), pack2(a0.z, a0.w),
                 pack2(a1.x, a1.y), pack2(a1.z, a1.w) };
    *(u32x4*)(As + (size_t)i * 8) = uv;
  }
  __syncthreads();

  for (int nbo = 0; nbo < 3; ++nbo) {
    const int nb = nbase + nbo;
    for (int i = t; i < 2048; i += 256) {
      const int kt = i >> 8, rem = i & 255, r2 = rem >> 2, rqv = rem & 3;
      const float* src = Wih + (size_t)(nb * 64 + r2) * Ee + kt * 32 + rqv * 8;
      const float4 b0 = *(const float4*)src;
      const float4 b1 = *(const float4*)(src + 4);
      u32x4 uv = { pack2(b0.x, b0.y), pack2(b0.z, b0.w),
                   pack2(b1.x, b1.y), pack2(b1.z, b1.w) };
      *(u32x4*)(Bs + (size_t)i * 8) = uv;
    }
    __syncthreads();

    f32x4 zero4 = {0.f, 0.f, 0.f, 0.f};
    f32x4 acc[2][4];
#pragma unroll
    for (int mt = 0; mt < 2; ++mt)
#pragma unroll
      for (int nt = 0; nt < 4; ++nt) acc[mt][nt] = zero4;

#pragma unroll
    for (int kt = 0; kt < 8; ++kt) {
      bf16x8 af[2], bfr[4];
#pragma unroll
      for (int mt = 0; mt < 2; ++mt)
        af[mt] = *(const bf16x8*)(As + ((size_t)kt * 512 + (w * 32 + mt * 16 + cl) * 4 + rq) * 8);
#pragma unroll
      for (int nt = 0; nt < 4; ++nt)
        bfr[nt] = *(const bf16x8*)(Bs + ((size_t)kt * 256 + (nt * 16 + cl) * 4 + rq) * 8);
#pragma unroll
      for (int mt = 0; mt < 2; ++mt)
#pragma unroll
        for (int nt = 0; nt < 4; ++nt)
          acc[mt][nt] = __builtin_amdgcn_mfma_f32_16x16x32_bf16(af[mt], bfr[nt], acc[mt][nt], 0, 0, 0);
    }

#pragma unroll
    for (int mt = 0; mt < 2; ++mt)
#pragma unroll
      for (int nt = 0; nt < 4; ++nt) {
        const int col = nb * 64 + nt * 16 + cl;
        float bias = bih[col];
        if (col < 512) bias += bhh[col];
#pragma unroll
        for (int q = 0; q < 4; ++q) {
          const int row = m0 + w * 32 + mt * 16 + rq * 4 + q;
          if (row < Vv) Pd[(size_t)row * Gg + col] = f2bf(acc[mt][nt][q] + bias);
        }
      }
    __syncthreads();
  }
}

// ---------------- K2: bidirectional GRU recurrence ----------------
// 8 blocks (dir = blk>>2, 16 batch rows), 512 threads = 8 waves, 1 WG/CU,
// FORCED 2 waves/SIMD via amdgpu_waves_per_eu(2,2) -> 256-VGPR budget/wave.
// wfrag = 192 regs/lane genuinely register-resident (r1-r6 ran this geometry
// at a heuristic 128-reg cap: ~130 regs spilled to scratch; WRITE_SIZE ~4MB
// spill stores + per-step L2 reload was the hidden ~7000 cyc/step tax).
// hprev and b_hh_n read from LDS to keep live regs ~250 < 256.
__global__ __launch_bounds__(512) __attribute__((amdgpu_waves_per_eu(2, 2)))
void k2_rec(
    const int* __restrict__ seqs, const int* __restrict__ lens,
    const float* __restrict__ Whh_f, const float* __restrict__ Whh_b,
    const float* __restrict__ bhh_f, const float* __restrict__ bhh_b,
    const u16* __restrict__ Pf, const u16* __restrict__ Pb,
    float* __restrict__ rep)
{
  const int tid = threadIdx.x, w = tid >> 6, l = tid & 63;
  const int cl = l & 15, rq = l >> 4;
  const int dir = (int)blockIdx.x >> 2;
  const int b0 = ((int)blockIdx.x & 3) * 16;

  const float* Whh = dir ? Whh_b : Whh_f;
  const float* bhh = dir ? bhh_b : bhh_f;
  const u16* P = dir ? Pb : Pf;

  __shared__ __align__(16) u16 h_lds[8192];    // 16 KB: 2 bufs x [kb][row][j^]
  __shared__ __align__(16) float bhn_lds[256]; // b_hh_n (n-gate cols)

  // ---- W_hh A-fragments: 3 gates x 2 units x 8 kb = 192 regs/lane ----
  bf16x8 wfrag[3][2][8];
#pragma unroll
  for (int g = 0; g < 3; ++g)
#pragma unroll
    for (int bi = 0; bi < 2; ++bi) {
      const int c = g * 256 + (2 * w + bi) * 16 + cl;
      const float* wr = Whh + (size_t)c * Hh;
#pragma unroll
      for (int kb = 0; kb < 8; ++kb) {
        const int k0 = kb * 32 + rq * 8;
        const float4 f0 = *(const float4*)(wr + k0);
        const float4 f1 = *(const float4*)(wr + k0 + 4);
        u32x4 uv = { pack2(f0.x, f0.y), pack2(f0.z, f0.w),
                     pack2(f1.x, f1.y), pack2(f1.z, f1.w) };
        wfrag[g][bi][kb] = __builtin_bit_cast(bf16x8, uv);
      }
    }

  if (tid < 256) bhn_lds[tid] = bhh[512 + tid];

  const int myrow = b0 + cl;
  const int mylen = lens[myrow];
  const int* myseq = seqs + (size_t)myrow * Tt;
  const int vthr = Tt - mylen;

  for (int i = tid; i < 4096; i += 512) ((u32*)h_lds)[i] = 0;

  // lane LDS byte offsets (XOR-swizzled fragment layout; verified r3-r7)
  const int xk = (cl >> 1);
  const int rdoff = cl * 64 + (((rq + xk) & 3) << 4);            // + kb*1024
  const int wr0 = w * 1024 + cl * 64 + ((((rq >> 1) + xk) & 3) << 4) + (rq & 1) * 8;
  const int wr1 = w * 1024 + cl * 64 + ((((rq >> 1) + 2 + xk) & 3) << 4) + (rq & 1) * 8;

  const int colb0 = w * 32 + rq * 4;   // u16 offset of bi=0 gi chunk in a P row

  // ---- prologue: gi(0) into regs; token for step 1 ----
  u32x2 gi0[3], gi1[3];
  {
    const int tk = myseq[dir ? (Tt - 1) : 0];
    const int valid = dir ? (0 < mylen) : (0 >= vthr);
    const u32 off = (valid ? (u32)tk : (u32)Vv) * (u32)(Gg * 2);
    const u16* pr = (const u16*)((const char*)P + off) + colb0;
#pragma unroll
    for (int g = 0; g < 3; ++g) {
      gi0[g] = *(const u32x2*)(pr + g * 256);
      gi1[g] = *(const u32x2*)(pr + g * 256 + 16);
    }
  }
  int tok1 = myseq[dir ? (Tt - 2) : 1];
  block_sync_lds();

  int bb = 0;
  for (int s = 0; s < Tt; ++s) {
    const char* hb = (const char*)h_lds + bb;
    char* hn = (char*)h_lds + (bb ^ 8192);

    // ---- MFMA phase: 2-deep pipelined h-fragment stream, no VMEM deps ----
    f32x4 zero4 = {0.f, 0.f, 0.f, 0.f};
    f32x4 ar0 = zero4, az0 = zero4, an0 = zero4;
    f32x4 ar1 = zero4, az1 = zero4, an1 = zero4;

    bf16x8 hA = *(const bf16x8*)(hb + rdoff);          // kb = 0
    bf16x8 hB;
#pragma unroll
    for (int kb = 0; kb < 8; kb += 2) {
      hB = *(const bf16x8*)(hb + (kb + 1) * 1024 + rdoff);
      ar0 = __builtin_amdgcn_mfma_f32_16x16x32_bf16(wfrag[0][0][kb], hA, ar0, 0, 0, 0);
      az0 = __builtin_amdgcn_mfma_f32_16x16x32_bf16(wfrag[1][0][kb], hA, az0, 0, 0, 0);
      an0 = __builtin_amdgcn_mfma_f32_16x16x32_bf16(wfrag[2][0][kb], hA, an0, 0, 0, 0);
      ar1 = __builtin_amdgcn_mfma_f32_16x16x32_bf16(wfrag[0][1][kb], hA, ar1, 0, 0, 0);
      az1 = __builtin_amdgcn_mfma_f32_16x16x32_bf16(wfrag[1][1][kb], hA, az1, 0, 0, 0);
      an1 = __builtin_amdgcn_mfma_f32_16x16x32_bf16(wfrag[2][1][kb], hA, an1, 0, 0, 0);
      if (kb + 2 < 8) hA = *(const bf16x8*)(hb + (kb + 2) * 1024 + rdoff);
      ar0 = __builtin_amdgcn_mfma_f32_16x16x32_bf16(wfrag[0][0][kb + 1], hB, ar0, 0, 0, 0);
      az0 = __builtin_amdgcn_mfma_f32_16x16x32_bf16(wfrag[1][0][kb + 1], hB, az0, 0, 0, 0);
      an0 = __builtin_amdgcn_mfma_f32_16x16x32_bf16(wfrag[2][0][kb + 1], hB, an0, 0, 0, 0);
      ar1 = __builtin_amdgcn_mfma_f32_16x16x32_bf16(wfrag[0][1][kb + 1], hB, ar1, 0, 0, 0);
      az1 = __builtin_amdgcn_mfma_f32_16x16x32_bf16(wfrag[1][1][kb + 1], hB, az1, 0, 0, 0);
      an1 = __builtin_amdgcn_mfma_f32_16x16x32_bf16(wfrag[2][1][kb + 1], hB, an1, 0, 0, 0);
    }

    // token for s+2
    int tok2 = tok1;
    if (s + 2 < Tt) tok2 = myseq[dir ? (Tt - 3 - s) : (s + 2)];

    // gi row pointer for s+1
    const int validn = dir ? (s + 1 < mylen) : (s + 1 >= vthr);
    const u32 offn = (validn ? (u32)tok1 : (u32)Vv) * (u32)(Gg * 2);
    const u16* prn = (const u16*)((const char*)P + offn) + colb0;

    // ---- GATES (hprev + b_hh_n from LDS; gi reload at tail) ----
#define GATES(BI, GIS, AR, AZ, AN, WRO, PRADD)                                   \
    {                                                                            \
      const f32x4 bhnv = *(const f32x4*)((const char*)bhn_lds + (2 * w + BI) * 64 + rq * 16); \
      const u32x2 hp = *(const u32x2*)(hb + WRO);                                \
      float hq[4];                                                               \
      _Pragma("unroll")                                                          \
      for (int q = 0; q < 4; ++q) {                                              \
        const u32 wr_ = (q & 2) ? GIS[0][1] : GIS[0][0];                         \
        const u32 wz_ = (q & 2) ? GIS[1][1] : GIS[1][0];                         \
        const u32 wn_ = (q & 2) ? GIS[2][1] : GIS[2][0];                         \
        const float ir = (q & 1) ? bfhi(wr_) : bflo(wr_);                        \
        const float iz = (q & 1) ? bfhi(wz_) : bflo(wz_);                        \
        const float in_ = (q & 1) ? bfhi(wn_) : bflo(wn_);                       \
        const float r = sigm(ir + AR[q]);                                        \
        const float z = sigm(iz + AZ[q]);                                        \
        const float t_ = fmaf(r, bhnv[q], in_);                                  \
        const float n = tanh_fast(fmaf(r, AN[q], t_));                           \
        const float hpq = (q & 1) ? bfhi(hp[q >> 1]) : bflo(hp[q >> 1]);         \
        hq[q] = fmaf(z, hpq - n, n);                                             \
      }                                                                          \
      u32 p0, p1;                                                                \
      asm("v_cvt_pk_bf16_f32 %0, %1, %2" : "=v"(p0) : "v"(hq[0]), "v"(hq[1]));   \
      asm("v_cvt_pk_bf16_f32 %0, %1, %2" : "=v"(p1) : "v"(hq[2]), "v"(hq[3]));   \
      u32x2 hw = {p0, p1};                                                       \
      *(u32x2*)(hn + WRO) = hw;                                                  \
      _Pragma("unroll")                                                          \
      for (int g = 0; g < 3; ++g) GIS[g] = *(const u32x2*)(prn + g * 256 + PRADD); \
    }

    GATES(0, gi0, ar0, az0, an0, wr0, 0)
    GATES(1, gi1, ar1, az1, an1, wr1, 16)
#undef GATES

    tok1 = tok2;
    bb ^= 8192;
    block_sync_lds();
  }

  // ---- final h (buffer 0, this lane's own slots) -> rep ----
  {
    const char* hf_ = (const char*)h_lds;    // Tt even -> final state in buf 0
    const u32x2 f0 = *(const u32x2*)(hf_ + wr0);
    const u32x2 f1 = *(const u32x2*)(hf_ + wr1);
    float* rp = rep + (size_t)(b0 + cl) * (2 * Hh) + dir * Hh + w * 32 + rq * 4;
    rp[0]  = bflo(f0[0]); rp[1]  = bfhi(f0[0]); rp[2]  = bflo(f0[1]); rp[3]  = bfhi(f0[1]);
    rp[16] = bflo(f1[0]); rp[17] = bfhi(f1[0]); rp[18] = bflo(f1[1]); rp[19] = bfhi(f1[1]);
  }
}

// ---------------- K3a: h1 = relu(rep @ W1^T + b1) ----------------
__global__ __launch_bounds__(256) void k3a(
    const float* __restrict__ rep, const float* __restrict__ W1,
    const float* __restrict__ b1, float* __restrict__ h1)
{
  __shared__ float rl[512];
  const int b = blockIdx.x, t = threadIdx.x;
  rl[t] = rep[(size_t)b * 512 + t];
  rl[t + 256] = rep[(size_t)b * 512 + 256 + t];
  __syncthreads();
#pragma unroll
  for (int oo = 0; oo < 2; ++oo) {
    const int o = t + oo * 256;
    const float4* wr = (const float4*)(W1 + (size_t)o * 512);
    const float4* rr = (const float4*)rl;
    float acc = 0.f;
#pragma unroll 8
    for (int k = 0; k < 128; ++k) {
      const float4 wv = wr[k], rv = rr[k];
      acc += wv.x * rv.x + wv.y * rv.y + wv.z * rv.z + wv.w * rv.w;
    }
    h1[(size_t)b * 512 + o] = fmaxf(acc + b1[o], 0.f);
  }
}

// ---------------- K3b: out = softmax(h1 @ W2^T + b2) ----------------
__global__ __launch_bounds__(320) void k3b(
    const float* __restrict__ h1, const float* __restrict__ W2,
    const float* __restrict__ b2, float* __restrict__ out)
{
  __shared__ float lg[64 * 5];
  const int t = threadIdx.x;      // 320 = 5 classes x 64 batch
  const int c = t >> 6, b = t & 63;
  const float4* hr = (const float4*)(h1 + (size_t)b * 512);
  const float4* wr = (const float4*)(W2 + (size_t)c * 512);
  float acc = 0.f;
#pragma unroll 8
  for (int k = 0; k < 128; ++k) {
    const float4 hv = hr[k], wv = wr[k];
    acc += hv.x * wv.x + hv.y * wv.y + hv.z * wv.z + hv.w * wv.w;
  }
  lg[b * 5 + c] = acc + b2[c];
  __syncthreads();
  if (t < 64) {
    float v[5];
#pragma unroll
    for (int i = 0; i < 5; ++i) v[i] = lg[t * 5 + i];
    float m = v[0];
#pragma unroll
    for (int i = 1; i < 5; ++i) m = fmaxf(m, v[i]);
    float ssum = 0.f;
#pragma unroll
    for (int i = 0; i < 5; ++i) {
      v[i] = __builtin_amdgcn_exp2f(1.44269504089f * (v[i] - m));
      ssum += v[i];
    }
    const float inv = 1.0f / ssum;
#pragma unroll
    for (int i = 0; i < 5; ++i) out[t * 5 + i] = v[i] * inv;
  }
}

extern "C" void kernel_launch(void* const* d_in, const int* in_sizes, int n_in,
                              void* d_out, int out_size, void* d_ws, size_t ws_size,
                              hipStream_t stream) {
  const int* seqs = (const int*)d_in[0];
  const int* lens = (const int*)d_in[1];
  const float* emb = (const float*)d_in[2];
  const float* Wih_f = (const float*)d_in[3];
  const float* Whh_f = (const float*)d_in[4];
  const float* bih_f = (const float*)d_in[5];
  const float* bhh_f = (const float*)d_in[6];
  const float* Wih_b = (const float*)d_in[7];
  const float* Whh_b = (const float*)d_in[8];
  const float* bih_b = (const float*)d_in[9];
  const float* bhh_b = (const float*)d_in[10];
  const float* W1 = (const float*)d_in[11];
  const float* b1 = (const float*)d_in[12];
  const float* W2 = (const float*)d_in[13];
  const float* b2 = (const float*)d_in[14];
  float* out = (float*)d_out;

  char* ws = (char*)d_ws;
  const size_t PSZ = (size_t)(Vv + 1) * Gg * 2;   // 76,801,536 B per direction
  u16* Pf = (u16*)ws;
  u16* Pb = (u16*)(ws + PSZ);
  float* rep = (float*)(ws + 2 * PSZ);
  float* h1 = (float*)(ws + 2 * PSZ + 131072);

  hipLaunchKernelGGL(k0_bias, dim3(3), dim3(256), 0, stream,
                     bih_f, bhh_f, bih_b, bhh_b, Pf, Pb);
  hipLaunchKernelGGL(k1_proj, dim3(391, 2, 4), dim3(256), 0, stream,
                     emb, Wih_f, Wih_b, bih_f, bhh_f, bih_b, bhh_b, Pf, Pb);
  hipLaunchKernelGGL(k2_rec, dim3(8), dim3(512), 0, stream,
                     seqs, lens, Whh_f, Whh_b, bhh_f, bhh_b, Pf, Pb, rep);
  hipLaunchKernelGGL(k3a, dim3(64), dim3(256), 0, stream, rep, W1, b1, h1);
  hipLaunchKernelGGL(k3b, dim3(1), dim3(320), 0, stream, h1, W2, b2, out);
}

// Round 9
// 5706.630 us; speedup vs baseline: 1.4277x; 1.0003x over previous
//
#include <hip/hip_runtime.h>
#include <stdint.h>

typedef uint32_t u32; typedef uint16_t u16;
typedef __attribute__((ext_vector_type(8))) __bf16 bf16x8;
typedef __attribute__((ext_vector_type(4))) float f32x4;
typedef __attribute__((ext_vector_type(2))) u32 u32x2;
typedef __attribute__((ext_vector_type(4))) u32 u32x4;

#define Vv 50000
#define Ee 256
#define Hh 256
#define Gg 768
#define Bb 64
#define Tt 2048

__device__ __forceinline__ u16 f2bf(float f) {
  u32 x = __builtin_bit_cast(u32, f);
  return (u16)((x + 0x7FFFu + ((x >> 16) & 1u)) >> 16);
}
__device__ __forceinline__ u32 pack2(float a, float b) {
  return (u32)f2bf(a) | ((u32)f2bf(b) << 16);
}
__device__ __forceinline__ float sigm(float x) {
  float e = __builtin_amdgcn_exp2f(-1.44269504089f * x);
  return __builtin_amdgcn_rcpf(1.0f + e);
}
__device__ __forceinline__ float tanh_fast(float x) {
  float e = __builtin_amdgcn_exp2f(2.88539008178f * x);
  return 1.0f - 2.0f * __builtin_amdgcn_rcpf(e + 1.0f);
}
__device__ __forceinline__ float bflo(u32 v) { return __builtin_bit_cast(float, v << 16); }
__device__ __forceinline__ float bfhi(u32 v) { return __builtin_bit_cast(float, v & 0xffff0000u); }

// LDS-only barrier: gi gather loads (lane-private) stay in flight across it.
__device__ __forceinline__ void block_sync_lds() {
  asm volatile("s_waitcnt lgkmcnt(0)" ::: "memory");
  __builtin_amdgcn_s_barrier();
  asm volatile("" ::: "memory");
}

// ---------------- K0: bias row (row Vv) of both P tables ----------------
__global__ void k0_bias(const float* __restrict__ bih_f, const float* __restrict__ bhh_f,
                        const float* __restrict__ bih_b, const float* __restrict__ bhh_b,
                        u16* __restrict__ Pf, u16* __restrict__ Pb) {
  int c = threadIdx.x + blockIdx.x * 256;
  if (c < Gg) {
    float bf_ = bih_f[c] + (c < 512 ? bhh_f[c] : 0.f);
    float bb_ = bih_b[c] + (c < 512 ? bhh_b[c] : 0.f);
    Pf[(size_t)Vv * Gg + c] = f2bf(bf_);
    Pb[(size_t)Vv * Gg + c] = f2bf(bb_);
  }
}

// ---------------- K1: P'[v,g] = emb[v]@W_ih^T + bias (bf16) ----------------
__global__ __launch_bounds__(256) void k1_proj(
    const float* __restrict__ emb, const float* __restrict__ Wih_f,
    const float* __restrict__ Wih_b,
    const float* __restrict__ bih_f, const float* __restrict__ bhh_f,
    const float* __restrict__ bih_b, const float* __restrict__ bhh_b,
    u16* __restrict__ Pf, u16* __restrict__ Pb)
{
  const int t = threadIdx.x, w = t >> 6, l = t & 63;
  const int cl = l & 15, rq = l >> 4;
  const int m0 = blockIdx.x * 128;
  const int dir = blockIdx.y;
  const int nbase = blockIdx.z * 3;
  const float* Wih = dir ? Wih_b : Wih_f;
  const float* bih = dir ? bih_b : bih_f;
  const float* bhh = dir ? bhh_b : bhh_f;
  u16* Pd = dir ? Pb : Pf;

  __shared__ __align__(16) u16 As[4096 * 8];
  __shared__ __align__(16) u16 Bs[2048 * 8];

  for (int i = t; i < 4096; i += 256) {
    const int kt = i >> 9, rem = i & 511, row = rem >> 2, rqv = rem & 3;
    const int gm = m0 + row;
    float4 a0 = {0.f,0.f,0.f,0.f}, a1 = {0.f,0.f,0.f,0.f};
    if (gm < Vv) {
      const float* src = emb + (size_t)gm * Ee + kt * 32 + rqv * 8;
      a0 = *(const float4*)src;
      a1 = *(const float4*)(src + 4);
    }
    u32x4 uv = { pack2(a0.x, a0.y), pack2(a0.z, a0.w),
                 pack2(a1.x, a1.y), pack2(a1.z, a1.w) };
    *(u32x4*)(As + (size_t)i * 8) = uv;
  }
  __syncthreads();

  for (int nbo = 0; nbo < 3; ++nbo) {
    const int nb = nbase + nbo;
    for (int i = t; i < 2048; i += 256) {
      const int kt = i >> 8, rem = i & 255, r2 = rem >> 2, rqv = rem & 3;
      const float* src = Wih + (size_t)(nb * 64 + r2) * Ee + kt * 32 + rqv * 8;
      const float4 b0 = *(const float4*)src;
      const float4 b1 = *(const float4*)(src + 4);
      u32x4 uv = { pack2(b0.x, b0.y), pack2(b0.z, b0.w),
                   pack2(b1.x, b1.y), pack2(b1.z, b1.w) };
      *(u32x4*)(Bs + (size_t)i * 8) = uv;
    }
    __syncthreads();

    f32x4 zero4 = {0.f, 0.f, 0.f, 0.f};
    f32x4 acc[2][4];
#pragma unroll
    for (int mt = 0; mt < 2; ++mt)
#pragma unroll
      for (int nt = 0; nt < 4; ++nt) acc[mt][nt] = zero4;

#pragma unroll
    for (int kt = 0; kt < 8; ++kt) {
      bf16x8 af[2], bfr[4];
#pragma unroll
      for (int mt = 0; mt < 2; ++mt)
        af[mt] = *(const bf16x8*)(As + ((size_t)kt * 512 + (w * 32 + mt * 16 + cl) * 4 + rq) * 8);
#pragma unroll
      for (int nt = 0; nt < 4; ++nt)
        bfr[nt] = *(const bf16x8*)(Bs + ((size_t)kt * 256 + (nt * 16 + cl) * 4 + rq) * 8);
#pragma unroll
      for (int mt = 0; mt < 2; ++mt)
#pragma unroll
        for (int nt = 0; nt < 4; ++nt)
          acc[mt][nt] = __builtin_amdgcn_mfma_f32_16x16x32_bf16(af[mt], bfr[nt], acc[mt][nt], 0, 0, 0);
    }

#pragma unroll
    for (int mt = 0; mt < 2; ++mt)
#pragma unroll
      for (int nt = 0; nt < 4; ++nt) {
        const int col = nb * 64 + nt * 16 + cl;
        float bias = bih[col];
        if (col < 512) bias += bhh[col];
#pragma unroll
        for (int q = 0; q < 4; ++q) {
          const int row = m0 + w * 32 + mt * 16 + rq * 4 + q;
          if (row < Vv) Pd[(size_t)row * Gg + col] = f2bf(acc[mt][nt][q] + bias);
        }
      }
    __syncthreads();
  }
}

// ---------------- K2: bidirectional GRU recurrence ----------------
// 8 blocks (dir = blk>>2, 16 batch rows), 512 threads = 8 waves, 1 WG/CU.
// __launch_bounds__(512, 1): min-waves-per-EU = 1 -> 256 arch-VGPR cap
// (allocator formula fitted from r1/r2/r7/r8: cap = 256/min_waves; every
// earlier 512-thread round pinned min=2 -> 128-reg cap -> ~140 regs of
// wfrag spilled to scratch -> ~390KB/CU/step L2 reload = the 5-6ms band).
// Hardware residency stays 2 waves/SIMD (8-wave workgroup, 512-reg file).
// wfrag 192 regs genuinely register-resident; working set ~65.
__global__ __launch_bounds__(512, 1)
void k2_rec(
    const int* __restrict__ seqs, const int* __restrict__ lens,
    const float* __restrict__ Whh_f, const float* __restrict__ Whh_b,
    const float* __restrict__ bhh_f, const float* __restrict__ bhh_b,
    const u16* __restrict__ Pf, const u16* __restrict__ Pb,
    float* __restrict__ rep)
{
  const int tid = threadIdx.x, w = tid >> 6, l = tid & 63;
  const int cl = l & 15, rq = l >> 4;
  const int dir = (int)blockIdx.x >> 2;
  const int b0 = ((int)blockIdx.x & 3) * 16;

  const float* Whh = dir ? Whh_b : Whh_f;
  const float* bhh = dir ? bhh_b : bhh_f;
  const u16* P = dir ? Pb : Pf;

  __shared__ __align__(16) u16 h_lds[8192];    // 16 KB: 2 bufs x [kb][row][j^]
  __shared__ __align__(16) float bhn_lds[256]; // b_hh_n (n-gate cols)

  // ---- W_hh A-fragments: 3 gates x 2 units x 8 kb = 192 regs/lane ----
  bf16x8 wfrag[3][2][8];
#pragma unroll
  for (int g = 0; g < 3; ++g)
#pragma unroll
    for (int bi = 0; bi < 2; ++bi) {
      const int c = g * 256 + (2 * w + bi) * 16 + cl;
      const float* wr = Whh + (size_t)c * Hh;
#pragma unroll
      for (int kb = 0; kb < 8; ++kb) {
        const int k0 = kb * 32 + rq * 8;
        const float4 f0 = *(const float4*)(wr + k0);
        const float4 f1 = *(const float4*)(wr + k0 + 4);
        u32x4 uv = { pack2(f0.x, f0.y), pack2(f0.z, f0.w),
                     pack2(f1.x, f1.y), pack2(f1.z, f1.w) };
        wfrag[g][bi][kb] = __builtin_bit_cast(bf16x8, uv);
      }
    }

  if (tid < 256) bhn_lds[tid] = bhh[512 + tid];

  const int myrow = b0 + cl;
  const int mylen = lens[myrow];
  const int* myseq = seqs + (size_t)myrow * Tt;
  const int vthr = Tt - mylen;

  for (int i = tid; i < 4096; i += 512) ((u32*)h_lds)[i] = 0;

  // lane LDS byte offsets (XOR-swizzled fragment layout; verified r3-r8)
  const int xk = (cl >> 1);
  const int rdoff = cl * 64 + (((rq + xk) & 3) << 4);            // + kb*1024
  const int wr0 = w * 1024 + cl * 64 + ((((rq >> 1) + xk) & 3) << 4) + (rq & 1) * 8;
  const int wr1 = w * 1024 + cl * 64 + ((((rq >> 1) + 2 + xk) & 3) << 4) + (rq & 1) * 8;

  const int colb0 = w * 32 + rq * 4;   // u16 offset of bi=0 gi chunk in a P row

  // ---- prologue: gi(0) into regs; token for step 1 ----
  u32x2 gi0[3], gi1[3];
  {
    const int tk = myseq[dir ? (Tt - 1) : 0];
    const int valid = dir ? (0 < mylen) : (0 >= vthr);
    const u32 off = (valid ? (u32)tk : (u32)Vv) * (u32)(Gg * 2);
    const u16* pr = (const u16*)((const char*)P + off) + colb0;
#pragma unroll
    for (int g = 0; g < 3; ++g) {
      gi0[g] = *(const u32x2*)(pr + g * 256);
      gi1[g] = *(const u32x2*)(pr + g * 256 + 16);
    }
  }
  int tok1 = myseq[dir ? (Tt - 2) : 1];
  block_sync_lds();

  int bb = 0;
  for (int s = 0; s < Tt; ++s) {
    const char* hb = (const char*)h_lds + bb;
    char* hn = (char*)h_lds + (bb ^ 8192);

    // ---- MFMA phase: 2-deep pipelined h-fragment stream, no VMEM deps ----
    f32x4 zero4 = {0.f, 0.f, 0.f, 0.f};
    f32x4 ar0 = zero4, az0 = zero4, an0 = zero4;
    f32x4 ar1 = zero4, az1 = zero4, an1 = zero4;

    bf16x8 hA = *(const bf16x8*)(hb + rdoff);          // kb = 0
    bf16x8 hB;
#pragma unroll
    for (int kb = 0; kb < 8; kb += 2) {
      hB = *(const bf16x8*)(hb + (kb + 1) * 1024 + rdoff);
      ar0 = __builtin_amdgcn_mfma_f32_16x16x32_bf16(wfrag[0][0][kb], hA, ar0, 0, 0, 0);
      az0 = __builtin_amdgcn_mfma_f32_16x16x32_bf16(wfrag[1][0][kb], hA, az0, 0, 0, 0);
      an0 = __builtin_amdgcn_mfma_f32_16x16x32_bf16(wfrag[2][0][kb], hA, an0, 0, 0, 0);
      ar1 = __builtin_amdgcn_mfma_f32_16x16x32_bf16(wfrag[0][1][kb], hA, ar1, 0, 0, 0);
      az1 = __builtin_amdgcn_mfma_f32_16x16x32_bf16(wfrag[1][1][kb], hA, az1, 0, 0, 0);
      an1 = __builtin_amdgcn_mfma_f32_16x16x32_bf16(wfrag[2][1][kb], hA, an1, 0, 0, 0);
      if (kb + 2 < 8) hA = *(const bf16x8*)(hb + (kb + 2) * 1024 + rdoff);
      ar0 = __builtin_amdgcn_mfma_f32_16x16x32_bf16(wfrag[0][0][kb + 1], hB, ar0, 0, 0, 0);
      az0 = __builtin_amdgcn_mfma_f32_16x16x32_bf16(wfrag[1][0][kb + 1], hB, az0, 0, 0, 0);
      an0 = __builtin_amdgcn_mfma_f32_16x16x32_bf16(wfrag[2][0][kb + 1], hB, an0, 0, 0, 0);
      ar1 = __builtin_amdgcn_mfma_f32_16x16x32_bf16(wfrag[0][1][kb + 1], hB, ar1, 0, 0, 0);
      az1 = __builtin_amdgcn_mfma_f32_16x16x32_bf16(wfrag[1][1][kb + 1], hB, az1, 0, 0, 0);
      an1 = __builtin_amdgcn_mfma_f32_16x16x32_bf16(wfrag[2][1][kb + 1], hB, an1, 0, 0, 0);
    }

    // token for s+2
    int tok2 = tok1;
    if (s + 2 < Tt) tok2 = myseq[dir ? (Tt - 3 - s) : (s + 2)];

    // gi row pointer for s+1
    const int validn = dir ? (s + 1 < mylen) : (s + 1 >= vthr);
    const u32 offn = (validn ? (u32)tok1 : (u32)Vv) * (u32)(Gg * 2);
    const u16* prn = (const u16*)((const char*)P + offn) + colb0;

    // ---- GATES (hprev + b_hh_n from LDS; gi reload at tail) ----
#define GATES(BI, GIS, AR, AZ, AN, WRO, PRADD)                                   \
    {                                                                            \
      const f32x4 bhnv = *(const f32x4*)((const char*)bhn_lds + (2 * w + BI) * 64 + rq * 16); \
      const u32x2 hp = *(const u32x2*)(hb + WRO);                                \
      float hq[4];                                                               \
      _Pragma("unroll")                                                          \
      for (int q = 0; q < 4; ++q) {                                              \
        const u32 wr_ = (q & 2) ? GIS[0][1] : GIS[0][0];                         \
        const u32 wz_ = (q & 2) ? GIS[1][1] : GIS[1][0];                         \
        const u32 wn_ = (q & 2) ? GIS[2][1] : GIS[2][0];                         \
        const float ir = (q & 1) ? bfhi(wr_) : bflo(wr_);                        \
        const float iz = (q & 1) ? bfhi(wz_) : bflo(wz_);                        \
        const float in_ = (q & 1) ? bfhi(wn_) : bflo(wn_);                       \
        const float r = sigm(ir + AR[q]);                                        \
        const float z = sigm(iz + AZ[q]);                                        \
        const float t_ = fmaf(r, bhnv[q], in_);                                  \
        const float n = tanh_fast(fmaf(r, AN[q], t_));                           \
        const float hpq = (q & 1) ? bfhi(hp[q >> 1]) : bflo(hp[q >> 1]);         \
        hq[q] = fmaf(z, hpq - n, n);                                             \
      }                                                                          \
      u32 p0, p1;                                                                \
      asm("v_cvt_pk_bf16_f32 %0, %1, %2" : "=v"(p0) : "v"(hq[0]), "v"(hq[1]));   \
      asm("v_cvt_pk_bf16_f32 %0, %1, %2" : "=v"(p1) : "v"(hq[2]), "v"(hq[3]));   \
      u32x2 hw = {p0, p1};                                                       \
      *(u32x2*)(hn + WRO) = hw;                                                  \
      _Pragma("unroll")                                                          \
      for (int g = 0; g < 3; ++g) GIS[g] = *(const u32x2*)(prn + g * 256 + PRADD); \
    }

    GATES(0, gi0, ar0, az0, an0, wr0, 0)
    GATES(1, gi1, ar1, az1, an1, wr1, 16)
#undef GATES

    tok1 = tok2;
    bb ^= 8192;
    block_sync_lds();
  }

  // ---- final h (buffer 0, this lane's own slots) -> rep ----
  {
    const char* hf_ = (const char*)h_lds;    // Tt even -> final state in buf 0
    const u32x2 f0 = *(const u32x2*)(hf_ + wr0);
    const u32x2 f1 = *(const u32x2*)(hf_ + wr1);
    float* rp = rep + (size_t)(b0 + cl) * (2 * Hh) + dir * Hh + w * 32 + rq * 4;
    rp[0]  = bflo(f0[0]); rp[1]  = bfhi(f0[0]); rp[2]  = bflo(f0[1]); rp[3]  = bfhi(f0[1]);
    rp[16] = bflo(f1[0]); rp[17] = bfhi(f1[0]); rp[18] = bflo(f1[1]); rp[19] = bfhi(f1[1]);
  }
}

// ---------------- K3a: h1 = relu(rep @ W1^T + b1) ----------------
__global__ __launch_bounds__(256) void k3a(
    const float* __restrict__ rep, const float* __restrict__ W1,
    const float* __restrict__ b1, float* __restrict__ h1)
{
  __shared__ float rl[512];
  const int b = blockIdx.x, t = threadIdx.x;
  rl[t] = rep[(size_t)b * 512 + t];
  rl[t + 256] = rep[(size_t)b * 512 + 256 + t];
  __syncthreads();
#pragma unroll
  for (int oo = 0; oo < 2; ++oo) {
    const int o = t + oo * 256;
    const float4* wr = (const float4*)(W1 + (size_t)o * 512);
    const float4* rr = (const float4*)rl;
    float acc = 0.f;
#pragma unroll 8
    for (int k = 0; k < 128; ++k) {
      const float4 wv = wr[k], rv = rr[k];
      acc += wv.x * rv.x + wv.y * rv.y + wv.z * rv.z + wv.w * rv.w;
    }
    h1[(size_t)b * 512 + o] = fmaxf(acc + b1[o], 0.f);
  }
}

// ---------------- K3b: out = softmax(h1 @ W2^T + b2) ----------------
__global__ __launch_bounds__(320) void k3b(
    const float* __restrict__ h1, const float* __restrict__ W2,
    const float* __restrict__ b2, float* __restrict__ out)
{
  __shared__ float lg[64 * 5];
  const int t = threadIdx.x;      // 320 = 5 classes x 64 batch
  const int c = t >> 6, b = t & 63;
  const float4* hr = (const float4*)(h1 + (size_t)b * 512);
  const float4* wr = (const float4*)(W2 + (size_t)c * 512);
  float acc = 0.f;
#pragma unroll 8
  for (int k = 0; k < 128; ++k) {
    const float4 hv = hr[k], wv = wr[k];
    acc += hv.x * wv.x + hv.y * wv.y + hv.z * wv.z + hv.w * wv.w;
  }
  lg[b * 5 + c] = acc + b2[c];
  __syncthreads();
  if (t < 64) {
    float v[5];
#pragma unroll
    for (int i = 0; i < 5; ++i) v[i] = lg[t * 5 + i];
    float m = v[0];
#pragma unroll
    for (int i = 1; i < 5; ++i) m = fmaxf(m, v[i]);
    float ssum = 0.f;
#pragma unroll
    for (int i = 0; i < 5; ++i) {
      v[i] = __builtin_amdgcn_exp2f(1.44269504089f * (v[i] - m));
      ssum += v[i];
    }
    const float inv = 1.0f / ssum;
#pragma unroll
    for (int i = 0; i < 5; ++i) out[t * 5 + i] = v[i] * inv;
  }
}

extern "C" void kernel_launch(void* const* d_in, const int* in_sizes, int n_in,
                              void* d_out, int out_size, void* d_ws, size_t ws_size,
                              hipStream_t stream) {
  const int* seqs = (const int*)d_in[0];
  const int* lens = (const int*)d_in[1];
  const float* emb = (const float*)d_in[2];
  const float* Wih_f = (const float*)d_in[3];
  const float* Whh_f = (const float*)d_in[4];
  const float* bih_f = (const float*)d_in[5];
  const float* bhh_f = (const float*)d_in[6];
  const float* Wih_b = (const float*)d_in[7];
  const float* Whh_b = (const float*)d_in[8];
  const float* bih_b = (const float*)d_in[9];
  const float* bhh_b = (const float*)d_in[10];
  const float* W1 = (const float*)d_in[11];
  const float* b1 = (const float*)d_in[12];
  const float* W2 = (const float*)d_in[13];
  const float* b2 = (const float*)d_in[14];
  float* out = (float*)d_out;

  char* ws = (char*)d_ws;
  const size_t PSZ = (size_t)(Vv + 1) * Gg * 2;   // 76,801,536 B per direction
  u16* Pf = (u16*)ws;
  u16* Pb = (u16*)(ws + PSZ);
  float* rep = (float*)(ws + 2 * PSZ);
  float* h1 = (float*)(ws + 2 * PSZ + 131072);

  hipLaunchKernelGGL(k0_bias, dim3(3), dim3(256), 0, stream,
                     bih_f, bhh_f, bih_b, bhh_b, Pf, Pb);
  hipLaunchKernelGGL(k1_proj, dim3(391, 2, 4), dim3(256), 0, stream,
                     emb, Wih_f, Wih_b, bih_f, bhh_f, bih_b, bhh_b, Pf, Pb);
  hipLaunchKernelGGL(k2_rec, dim3(8), dim3(512), 0, stream,
                     seqs, lens, Whh_f, Whh_b, bhh_f, bhh_b, Pf, Pb, rep);
  hipLaunchKernelGGL(k3a, dim3(64), dim3(256), 0, stream, rep, W1, b1, h1);
  hipLaunchKernelGGL(k3b, dim3(1), dim3(320), 0, stream, h1, W2, b2, out);
}

// Round 10
// 5676.872 us; speedup vs baseline: 1.4352x; 1.0052x over previous
//
#include <hip/hip_runtime.h>
#include <stdint.h>

typedef uint32_t u32; typedef uint16_t u16;
typedef __attribute__((ext_vector_type(8))) __bf16 bf16x8;
typedef __attribute__((ext_vector_type(4))) float f32x4;
typedef __attribute__((ext_vector_type(2))) u32 u32x2;
typedef __attribute__((ext_vector_type(4))) u32 u32x4;

#define Vv 50000
#define Ee 256
#define Hh 256
#define Gg 768
#define Bb 64
#define Tt 2048

__device__ __forceinline__ u16 f2bf(float f) {
  u32 x = __builtin_bit_cast(u32, f);
  return (u16)((x + 0x7FFFu + ((x >> 16) & 1u)) >> 16);
}
__device__ __forceinline__ u32 pack2(float a, float b) {
  return (u32)f2bf(a) | ((u32)f2bf(b) << 16);
}
__device__ __forceinline__ float sigm(float x) {
  float e = __builtin_amdgcn_exp2f(-1.44269504089f * x);
  return __builtin_amdgcn_rcpf(1.0f + e);
}
__device__ __forceinline__ float tanh_fast(float x) {
  float e = __builtin_amdgcn_exp2f(2.88539008178f * x);
  return 1.0f - 2.0f * __builtin_amdgcn_rcpf(e + 1.0f);
}
__device__ __forceinline__ float bflo(u32 v) { return __builtin_bit_cast(float, v << 16); }
__device__ __forceinline__ float bfhi(u32 v) { return __builtin_bit_cast(float, v & 0xffff0000u); }

// LDS-only barrier: gi gather loads (lane-private) stay in flight across it.
__device__ __forceinline__ void block_sync_lds() {
  asm volatile("s_waitcnt lgkmcnt(0)" ::: "memory");
  __builtin_amdgcn_s_barrier();
  asm volatile("" ::: "memory");
}

// MFMA with A-operand pinned to AGPRs (gfx950: A may come from AGPR directly).
// This forces the weight fragments' live ranges into the AGPR half of the
// unified file, leaving the arch-VGPR budget (<=128 at 2 waves/SIMD as the
// compiler allocates it) entirely to the ~64-reg working set -> no spill.
#define MFMA_AV(ACC, W, HF) \
  asm("v_mfma_f32_16x16x32_bf16 %0, %1, %2, %0" : "+v"(ACC) : "a"(W), "v"(HF))

// ---------------- K0: bias row (row Vv) of both P tables ----------------
__global__ void k0_bias(const float* __restrict__ bih_f, const float* __restrict__ bhh_f,
                        const float* __restrict__ bih_b, const float* __restrict__ bhh_b,
                        u16* __restrict__ Pf, u16* __restrict__ Pb) {
  int c = threadIdx.x + blockIdx.x * 256;
  if (c < Gg) {
    float bf_ = bih_f[c] + (c < 512 ? bhh_f[c] : 0.f);
    float bb_ = bih_b[c] + (c < 512 ? bhh_b[c] : 0.f);
    Pf[(size_t)Vv * Gg + c] = f2bf(bf_);
    Pb[(size_t)Vv * Gg + c] = f2bf(bb_);
  }
}

// ---------------- K1: P'[v,g] = emb[v]@W_ih^T + bias (bf16) ----------------
__global__ __launch_bounds__(256) void k1_proj(
    const float* __restrict__ emb, const float* __restrict__ Wih_f,
    const float* __restrict__ Wih_b,
    const float* __restrict__ bih_f, const float* __restrict__ bhh_f,
    const float* __restrict__ bih_b, const float* __restrict__ bhh_b,
    u16* __restrict__ Pf, u16* __restrict__ Pb)
{
  const int t = threadIdx.x, w = t >> 6, l = t & 63;
  const int cl = l & 15, rq = l >> 4;
  const int m0 = blockIdx.x * 128;
  const int dir = blockIdx.y;
  const int nbase = blockIdx.z * 3;
  const float* Wih = dir ? Wih_b : Wih_f;
  const float* bih = dir ? bih_b : bih_f;
  const float* bhh = dir ? bhh_b : bhh_f;
  u16* Pd = dir ? Pb : Pf;

  __shared__ __align__(16) u16 As[4096 * 8];
  __shared__ __align__(16) u16 Bs[2048 * 8];

  for (int i = t; i < 4096; i += 256) {
    const int kt = i >> 9, rem = i & 511, row = rem >> 2, rqv = rem & 3;
    const int gm = m0 + row;
    float4 a0 = {0.f,0.f,0.f,0.f}, a1 = {0.f,0.f,0.f,0.f};
    if (gm < Vv) {
      const float* src = emb + (size_t)gm * Ee + kt * 32 + rqv * 8;
      a0 = *(const float4*)src;
      a1 = *(const float4*)(src + 4);
    }
    u32x4 uv = { pack2(a0.x, a0.y), pack2(a0.z, a0.w),
                 pack2(a1.x, a1.y), pack2(a1.z, a1.w) };
    *(u32x4*)(As + (size_t)i * 8) = uv;
  }
  __syncthreads();

  for (int nbo = 0; nbo < 3; ++nbo) {
    const int nb = nbase + nbo;
    for (int i = t; i < 2048; i += 256) {
      const int kt = i >> 8, rem = i & 255, r2 = rem >> 2, rqv = rem & 3;
      const float* src = Wih + (size_t)(nb * 64 + r2) * Ee + kt * 32 + rqv * 8;
      const float4 b0 = *(const float4*)src;
      const float4 b1 = *(const float4*)(src + 4);
      u32x4 uv = { pack2(b0.x, b0.y), pack2(b0.z, b0.w),
                   pack2(b1.x, b1.y), pack2(b1.z, b1.w) };
      *(u32x4*)(Bs + (size_t)i * 8) = uv;
    }
    __syncthreads();

    f32x4 zero4 = {0.f, 0.f, 0.f, 0.f};
    f32x4 acc[2][4];
#pragma unroll
    for (int mt = 0; mt < 2; ++mt)
#pragma unroll
      for (int nt = 0; nt < 4; ++nt) acc[mt][nt] = zero4;

#pragma unroll
    for (int kt = 0; kt < 8; ++kt) {
      bf16x8 af[2], bfr[4];
#pragma unroll
      for (int mt = 0; mt < 2; ++mt)
        af[mt] = *(const bf16x8*)(As + ((size_t)kt * 512 + (w * 32 + mt * 16 + cl) * 4 + rq) * 8);
#pragma unroll
      for (int nt = 0; nt < 4; ++nt)
        bfr[nt] = *(const bf16x8*)(Bs + ((size_t)kt * 256 + (nt * 16 + cl) * 4 + rq) * 8);
#pragma unroll
      for (int mt = 0; mt < 2; ++mt)
#pragma unroll
        for (int nt = 0; nt < 4; ++nt)
          acc[mt][nt] = __builtin_amdgcn_mfma_f32_16x16x32_bf16(af[mt], bfr[nt], acc[mt][nt], 0, 0, 0);
    }

#pragma unroll
    for (int mt = 0; mt < 2; ++mt)
#pragma unroll
      for (int nt = 0; nt < 4; ++nt) {
        const int col = nb * 64 + nt * 16 + cl;
        float bias = bih[col];
        if (col < 512) bias += bhh[col];
#pragma unroll
        for (int q = 0; q < 4; ++q) {
          const int row = m0 + w * 32 + mt * 16 + rq * 4 + q;
          if (row < Vv) Pd[(size_t)row * Gg + col] = f2bf(acc[mt][nt][q] + bias);
        }
      }
    __syncthreads();
  }
}

// ---------------- K2: bidirectional GRU recurrence ----------------
// 8 blocks (dir = blk>>2, 16 batch rows), 512 threads = 8 waves, 1 WG/CU.
// W_hh fragments (192 regs/lane) pinned in AGPRs via inline-asm "a"
// constraints; MFMA reads A straight from AGPR (gfx950 unified file).
// Arch-VGPR working set ~64 -> per-wave total ~256 = the exact 2-wave/SIMD
// budget; no spill (r1-r9: compiler capped arch VGPRs at 128 and spilled
// ~130 wfrag regs to scratch -> WRITE_SIZE ~4MB + per-step L2 reloads).
__global__ __launch_bounds__(512, 1)
void k2_rec(
    const int* __restrict__ seqs, const int* __restrict__ lens,
    const float* __restrict__ Whh_f, const float* __restrict__ Whh_b,
    const float* __restrict__ bhh_f, const float* __restrict__ bhh_b,
    const u16* __restrict__ Pf, const u16* __restrict__ Pb,
    float* __restrict__ rep)
{
  const int tid = threadIdx.x, w = tid >> 6, l = tid & 63;
  const int cl = l & 15, rq = l >> 4;
  const int dir = (int)blockIdx.x >> 2;
  const int b0 = ((int)blockIdx.x & 3) * 16;

  const float* Whh = dir ? Whh_b : Whh_f;
  const float* bhh = dir ? bhh_b : bhh_f;
  const u16* P = dir ? Pb : Pf;

  __shared__ __align__(16) u16 h_lds[8192];    // 16 KB: 2 bufs x [kb][row][j^]
  __shared__ __align__(16) float bhn_lds[256]; // b_hh_n (n-gate cols)

  // ---- W_hh A-fragments: 48 frags x 4 regs = 192, AGPR-resident ----
  bf16x8 wfrag[3][2][8];
#pragma unroll
  for (int g = 0; g < 3; ++g)
#pragma unroll
    for (int bi = 0; bi < 2; ++bi) {
      const int c = g * 256 + (2 * w + bi) * 16 + cl;
      const float* wr = Whh + (size_t)c * Hh;
#pragma unroll
      for (int kb = 0; kb < 8; ++kb) {
        const int k0 = kb * 32 + rq * 8;
        const float4 f0 = *(const float4*)(wr + k0);
        const float4 f1 = *(const float4*)(wr + k0 + 4);
        u32x4 uv = { pack2(f0.x, f0.y), pack2(f0.z, f0.w),
                     pack2(f1.x, f1.y), pack2(f1.z, f1.w) };
        wfrag[g][bi][kb] = __builtin_bit_cast(bf16x8, uv);
        // pin this fragment's live range to the AGPR class now
        asm("" : "+a"(wfrag[g][bi][kb]));
      }
    }

  if (tid < 256) bhn_lds[tid] = bhh[512 + tid];

  const int myrow = b0 + cl;
  const int mylen = lens[myrow];
  const int* myseq = seqs + (size_t)myrow * Tt;
  const int vthr = Tt - mylen;

  for (int i = tid; i < 4096; i += 512) ((u32*)h_lds)[i] = 0;

  // lane LDS byte offsets (XOR-swizzled fragment layout; verified r3-r9)
  const int xk = (cl >> 1);
  const int rdoff = cl * 64 + (((rq + xk) & 3) << 4);            // + kb*1024
  const int wr0 = w * 1024 + cl * 64 + ((((rq >> 1) + xk) & 3) << 4) + (rq & 1) * 8;
  const int wr1 = w * 1024 + cl * 64 + ((((rq >> 1) + 2 + xk) & 3) << 4) + (rq & 1) * 8;

  const int colb0 = w * 32 + rq * 4;   // u16 offset of bi=0 gi chunk in a P row

  // ---- prologue: gi(0) into regs; token for step 1 ----
  u32x2 gi0[3], gi1[3];
  {
    const int tk = myseq[dir ? (Tt - 1) : 0];
    const int valid = dir ? (0 < mylen) : (0 >= vthr);
    const u32 off = (valid ? (u32)tk : (u32)Vv) * (u32)(Gg * 2);
    const u16* pr = (const u16*)((const char*)P + off) + colb0;
#pragma unroll
    for (int g = 0; g < 3; ++g) {
      gi0[g] = *(const u32x2*)(pr + g * 256);
      gi1[g] = *(const u32x2*)(pr + g * 256 + 16);
    }
  }
  int tok1 = myseq[dir ? (Tt - 2) : 1];
  block_sync_lds();

  int bb = 0;
  for (int s = 0; s < Tt; ++s) {
    const char* hb = (const char*)h_lds + bb;
    char* hn = (char*)h_lds + (bb ^ 8192);

    // ---- MFMA phase: A from AGPR, B streamed from LDS (2-deep), C in VGPR ----
    f32x4 zero4 = {0.f, 0.f, 0.f, 0.f};
    f32x4 ar0 = zero4, az0 = zero4, an0 = zero4;
    f32x4 ar1 = zero4, az1 = zero4, an1 = zero4;

    bf16x8 hA = *(const bf16x8*)(hb + rdoff);          // kb = 0
    bf16x8 hB;
#pragma unroll
    for (int kb = 0; kb < 8; kb += 2) {
      hB = *(const bf16x8*)(hb + (kb + 1) * 1024 + rdoff);
      MFMA_AV(ar0, wfrag[0][0][kb], hA);
      MFMA_AV(az0, wfrag[1][0][kb], hA);
      MFMA_AV(an0, wfrag[2][0][kb], hA);
      MFMA_AV(ar1, wfrag[0][1][kb], hA);
      MFMA_AV(az1, wfrag[1][1][kb], hA);
      MFMA_AV(an1, wfrag[2][1][kb], hA);
      if (kb + 2 < 8) hA = *(const bf16x8*)(hb + (kb + 2) * 1024 + rdoff);
      MFMA_AV(ar0, wfrag[0][0][kb + 1], hB);
      MFMA_AV(az0, wfrag[1][0][kb + 1], hB);
      MFMA_AV(an0, wfrag[2][0][kb + 1], hB);
      MFMA_AV(ar1, wfrag[0][1][kb + 1], hB);
      MFMA_AV(az1, wfrag[1][1][kb + 1], hB);
      MFMA_AV(an1, wfrag[2][1][kb + 1], hB);
    }

    // token for s+2
    int tok2 = tok1;
    if (s + 2 < Tt) tok2 = myseq[dir ? (Tt - 3 - s) : (s + 2)];

    // gi row pointer for s+1
    const int validn = dir ? (s + 1 < mylen) : (s + 1 >= vthr);
    const u32 offn = (validn ? (u32)tok1 : (u32)Vv) * (u32)(Gg * 2);
    const u16* prn = (const u16*)((const char*)P + offn) + colb0;

    // ---- GATES (hprev + b_hh_n from LDS; gi reload at tail) ----
#define GATES(BI, GIS, AR, AZ, AN, WRO, PRADD)                                   \
    {                                                                            \
      const f32x4 bhnv = *(const f32x4*)((const char*)bhn_lds + (2 * w + BI) * 64 + rq * 16); \
      const u32x2 hp = *(const u32x2*)(hb + WRO);                                \
      float hq[4];                                                               \
      _Pragma("unroll")                                                          \
      for (int q = 0; q < 4; ++q) {                                              \
        const u32 wr_ = (q & 2) ? GIS[0][1] : GIS[0][0];                         \
        const u32 wz_ = (q & 2) ? GIS[1][1] : GIS[1][0];                         \
        const u32 wn_ = (q & 2) ? GIS[2][1] : GIS[2][0];                         \
        const float ir = (q & 1) ? bfhi(wr_) : bflo(wr_);                        \
        const float iz = (q & 1) ? bfhi(wz_) : bflo(wz_);                        \
        const float in_ = (q & 1) ? bfhi(wn_) : bflo(wn_);                       \
        const float r = sigm(ir + AR[q]);                                        \
        const float z = sigm(iz + AZ[q]);                                        \
        const float t_ = fmaf(r, bhnv[q], in_);                                  \
        const float n = tanh_fast(fmaf(r, AN[q], t_));                           \
        const float hpq = (q & 1) ? bfhi(hp[q >> 1]) : bflo(hp[q >> 1]);         \
        hq[q] = fmaf(z, hpq - n, n);                                             \
      }                                                                          \
      u32 p0, p1;                                                                \
      asm("v_cvt_pk_bf16_f32 %0, %1, %2" : "=v"(p0) : "v"(hq[0]), "v"(hq[1]));   \
      asm("v_cvt_pk_bf16_f32 %0, %1, %2" : "=v"(p1) : "v"(hq[2]), "v"(hq[3]));   \
      u32x2 hw = {p0, p1};                                                       \
      *(u32x2*)(hn + WRO) = hw;                                                  \
      _Pragma("unroll")                                                          \
      for (int g = 0; g < 3; ++g) GIS[g] = *(const u32x2*)(prn + g * 256 + PRADD); \
    }

    GATES(0, gi0, ar0, az0, an0, wr0, 0)
    GATES(1, gi1, ar1, az1, an1, wr1, 16)
#undef GATES

    tok1 = tok2;
    bb ^= 8192;
    block_sync_lds();
  }

  // ---- final h (buffer 0, this lane's own slots) -> rep ----
  {
    const char* hf_ = (const char*)h_lds;    // Tt even -> final state in buf 0
    const u32x2 f0 = *(const u32x2*)(hf_ + wr0);
    const u32x2 f1 = *(const u32x2*)(hf_ + wr1);
    float* rp = rep + (size_t)(b0 + cl) * (2 * Hh) + dir * Hh + w * 32 + rq * 4;
    rp[0]  = bflo(f0[0]); rp[1]  = bfhi(f0[0]); rp[2]  = bflo(f0[1]); rp[3]  = bfhi(f0[1]);
    rp[16] = bflo(f1[0]); rp[17] = bfhi(f1[0]); rp[18] = bflo(f1[1]); rp[19] = bfhi(f1[1]);
  }
}

// ---------------- K3a: h1 = relu(rep @ W1^T + b1) ----------------
__global__ __launch_bounds__(256) void k3a(
    const float* __restrict__ rep, const float* __restrict__ W1,
    const float* __restrict__ b1, float* __restrict__ h1)
{
  __shared__ float rl[512];
  const int b = blockIdx.x, t = threadIdx.x;
  rl[t] = rep[(size_t)b * 512 + t];
  rl[t + 256] = rep[(size_t)b * 512 + 256 + t];
  __syncthreads();
#pragma unroll
  for (int oo = 0; oo < 2; ++oo) {
    const int o = t + oo * 256;
    const float4* wr = (const float4*)(W1 + (size_t)o * 512);
    const float4* rr = (const float4*)rl;
    float acc = 0.f;
#pragma unroll 8
    for (int k = 0; k < 128; ++k) {
      const float4 wv = wr[k], rv = rr[k];
      acc += wv.x * rv.x + wv.y * rv.y + wv.z * rv.z + wv.w * rv.w;
    }
    h1[(size_t)b * 512 + o] = fmaxf(acc + b1[o], 0.f);
  }
}

// ---------------- K3b: out = softmax(h1 @ W2^T + b2) ----------------
__global__ __launch_bounds__(320) void k3b(
    const float* __restrict__ h1, const float* __restrict__ W2,
    const float* __restrict__ b2, float* __restrict__ out)
{
  __shared__ float lg[64 * 5];
  const int t = threadIdx.x;      // 320 = 5 classes x 64 batch
  const int c = t >> 6, b = t & 63;
  const float4* hr = (const float4*)(h1 + (size_t)b * 512);
  const float4* wr = (const float4*)(W2 + (size_t)c * 512);
  float acc = 0.f;
#pragma unroll 8
  for (int k = 0; k < 128; ++k) {
    const float4 hv = hr[k], wv = wr[k];
    acc += hv.x * wv.x + hv.y * wv.y + hv.z * wv.z + hv.w * wv.w;
  }
  lg[b * 5 + c] = acc + b2[c];
  __syncthreads();
  if (t < 64) {
    float v[5];
#pragma unroll
    for (int i = 0; i < 5; ++i) v[i] = lg[t * 5 + i];
    float m = v[0];
#pragma unroll
    for (int i = 1; i < 5; ++i) m = fmaxf(m, v[i]);
    float ssum = 0.f;
#pragma unroll
    for (int i = 0; i < 5; ++i) {
      v[i] = __builtin_amdgcn_exp2f(1.44269504089f * (v[i] - m));
      ssum += v[i];
    }
    const float inv = 1.0f / ssum;
#pragma unroll
    for (int i = 0; i < 5; ++i) out[t * 5 + i] = v[i] * inv;
  }
}

extern "C" void kernel_launch(void* const* d_in, const int* in_sizes, int n_in,
                              void* d_out, int out_size, void* d_ws, size_t ws_size,
                              hipStream_t stream) {
  const int* seqs = (const int*)d_in[0];
  const int* lens = (const int*)d_in[1];
  const float* emb = (const float*)d_in[2];
  const float* Wih_f = (const float*)d_in[3];
  const float* Whh_f = (const float*)d_in[4];
  const float* bih_f = (const float*)d_in[5];
  const float* bhh_f = (const float*)d_in[6];
  const float* Wih_b = (const float*)d_in[7];
  const float* Whh_b = (const float*)d_in[8];
  const float* bih_b = (const float*)d_in[9];
  const float* bhh_b = (const float*)d_in[10];
  const float* W1 = (const float*)d_in[11];
  const float* b1 = (const float*)d_in[12];
  const float* W2 = (const float*)d_in[13];
  const float* b2 = (const float*)d_in[14];
  float* out = (float*)d_out;

  char* ws = (char*)d_ws;
  const size_t PSZ = (size_t)(Vv + 1) * Gg * 2;   // 76,801,536 B per direction
  u16* Pf = (u16*)ws;
  u16* Pb = (u16*)(ws + PSZ);
  float* rep = (float*)(ws + 2 * PSZ);
  float* h1 = (float*)(ws + 2 * PSZ + 131072);

  hipLaunchKernelGGL(k0_bias, dim3(3), dim3(256), 0, stream,
                     bih_f, bhh_f, bih_b, bhh_b, Pf, Pb);
  hipLaunchKernelGGL(k1_proj, dim3(391, 2, 4), dim3(256), 0, stream,
                     emb, Wih_f, Wih_b, bih_f, bhh_f, bih_b, bhh_b, Pf, Pb);
  hipLaunchKernelGGL(k2_rec, dim3(8), dim3(512), 0, stream,
                     seqs, lens, Whh_f, Whh_b, bhh_f, bhh_b, Pf, Pb, rep);
  hipLaunchKernelGGL(k3a, dim3(64), dim3(256), 0, stream, rep, W1, b1, h1);
  hipLaunchKernelGGL(k3b, dim3(1), dim3(320), 0, stream, h1, W2, b2, out);
}